// Round 1
// 2993.700 us; speedup vs baseline: 2.1062x; 2.1062x over previous
//
#include <hip/hip_runtime.h>

#define B_    64
#define S_    48
#define T_    48
#define E_    256
#define H_    512
#define G_    1536   // 3*H
#define VOUT_ 32000
#define NBLK_ 48     // persistent scan: 16 L0-blocks + 32 L1-blocks

typedef __attribute__((ext_vector_type(8))) short short8;
typedef __attribute__((ext_vector_type(4))) float f4;

__device__ inline unsigned short f2bf(float f) {
    unsigned u = __float_as_uint(f);
    u += 0x7fffu + ((u >> 16) & 1u);   // RNE
    return (unsigned short)(u >> 16);
}
__device__ inline unsigned pack2(float a, float b) {
    return (unsigned)f2bf(a) | ((unsigned)f2bf(b) << 16);
}

// ---------------------------------------------------------------- utility
__global__ void zero_f32(float* p, int n) {
    int i = blockIdx.x * 256 + threadIdx.x;
    if (i < n) p[i] = 0.f;
}

__global__ void zero_out_t0(float* out) {
    int v = blockIdx.x * 256 + threadIdx.x;
    int b = blockIdx.y;
    if (v < VOUT_) out[(size_t)b * T_ * VOUT_ + v] = 0.f;
}

// fp32 -> bf16, 4 elements/thread
__global__ void cvt_bf16(const float* __restrict__ s, unsigned short* __restrict__ d, int n4) {
    int i = blockIdx.x * 256 + threadIdx.x;
    if (i < n4) {
        float4 v = ((const float4*)s)[i];
        uint2 o;
        o.x = pack2(v.x, v.y);
        o.y = pack2(v.z, v.w);
        ((uint2*)d)[i] = o;
    }
}

// ---------------------------------------------------------------- MFMA GEMM
// C(M,N) = A(M,K) @ W(N,K)^T + bias   (used for gi precompute + logits)
__global__ __launch_bounds__(256)
void gemm64(const float* __restrict__ aF,
            const unsigned short* __restrict__ aB,
            const int* __restrict__ idx, int idx_stride,
            const unsigned short* __restrict__ Wb,
            const float* __restrict__ bias,
            float* __restrict__ outF,
            float* __restrict__ outR,
            int N, int K)
{
    __shared__ __align__(16) short As[64][40];
    __shared__ __align__(16) short Ws[64][40];
    const int tid  = threadIdx.x;
    const int m0   = blockIdx.x * 64;
    const int n0   = blockIdx.y * 64;
    const int row  = tid >> 2;
    const int col8 = (tid & 3) * 8;

    const float* apF = nullptr;
    const unsigned short* apB = nullptr;
    {
        int m = m0 + row;
        if (aF) {
            size_t r;
            if (idx) { int tt = m >> 6, b = m & 63; r = (size_t)idx[b * idx_stride + tt]; }
            else     { r = (size_t)m; }
            apF = aF + r * K + col8;
        } else {
            apB = aB + (size_t)m * K + col8;
        }
    }
    const unsigned short* wp = Wb + (size_t)(n0 + row) * K + col8;

    f4 acc[4];
    const f4 zz = {0.f, 0.f, 0.f, 0.f};
    acc[0] = zz; acc[1] = zz; acc[2] = zz; acc[3] = zz;

    const int wv   = tid >> 6;
    const int lane = tid & 63;
    const int quad = lane >> 4;
    const int l16  = lane & 15;

    for (int k0 = 0; k0 < K; k0 += 32) {
        uint4 av;
        if (apF) {
            float4 v0 = *(const float4*)(apF + k0);
            float4 v1 = *(const float4*)(apF + k0 + 4);
            av.x = pack2(v0.x, v0.y);
            av.y = pack2(v0.z, v0.w);
            av.z = pack2(v1.x, v1.y);
            av.w = pack2(v1.z, v1.w);
        } else {
            av = *(const uint4*)(apB + k0);
        }
        uint4 wvv = *(const uint4*)(wp + k0);
        *(uint4*)&As[row][col8] = av;
        *(uint4*)&Ws[row][col8] = wvv;
        __syncthreads();
        short8 afrag = *(const short8*)&As[wv * 16 + l16][quad * 8];
#pragma unroll
        for (int nt = 0; nt < 4; ++nt) {
            short8 bfrag = *(const short8*)&Ws[nt * 16 + l16][quad * 8];
            acc[nt] = __builtin_amdgcn_mfma_f32_16x16x32_bf16(afrag, bfrag, acc[nt], 0, 0, 0);
        }
        __syncthreads();
    }

#pragma unroll
    for (int nt = 0; nt < 4; ++nt) {
#pragma unroll
        for (int r = 0; r < 4; ++r) {
            int mm = m0 + wv * 16 + quad * 4 + r;
            int nn = n0 + nt * 16 + l16;
            float v = acc[nt][r];
            if (bias) v += bias[nn];
            if (outF) {
                outF[(size_t)mm * N + nn] = v;
            } else {
                int tt = mm >> 6, b = mm & 63;             // mm = t*64 + b
                outR[((size_t)b * T_ + tt + 1) * VOUT_ + nn] = v;
            }
        }
    }
}

// ---------------------------------------------------------------- persistent RNN scan
// Grid-wide barrier: monotonic counter, device(agent)-scope atomics.
// All NBLK_ (=48) blocks are trivially co-resident (48 << 256 CUs).
// Release: __threadfence() (L2 writeback) before arrive; acquire: __threadfence()
// (L2/L1 invalidate) after the spin — handles cross-XCD L2 non-coherence.
__device__ __forceinline__ void gsync(unsigned* bar, unsigned target) {
    __syncthreads();
    if (threadIdx.x == 0) {
        __threadfence();
        __hip_atomic_fetch_add(bar, 1u, __ATOMIC_RELAXED, __HIP_MEMORY_SCOPE_AGENT);
        while (__hip_atomic_load(bar, __ATOMIC_RELAXED, __HIP_MEMORY_SCOPE_AGENT) < target) {
            __builtin_amdgcn_s_sleep(1);
        }
        __threadfence();
    }
    __syncthreads();
}

// One GEMM phase: acc[g][nt] += A(64xH) @ W(3H x H)^T fragment-wise, straight
// from global (L2-resident), no LDS. Fragment indexing identical to the
// verified rnn_step: A row = wv*16+l16, k = quad*8; W row = g*H + j0+nt*16+l16.
// n-gate accumulates into acc[NIDX] (2 = input part, 3 = hidden part).
template<int NT, int NIDX>
__device__ inline void gphase(f4 (&acc)[4][2],
                              const unsigned short* __restrict__ A,
                              const unsigned short* __restrict__ W,
                              int rowA, int wbase, int quad8)
{
    const unsigned short* ap = A + (size_t)rowA * H_ + quad8;
    const unsigned short* wp = W + (size_t)wbase * H_ + quad8;
#pragma unroll 4
    for (int k = 0; k < H_; k += 32) {
        short8 af = *(const short8*)(ap + k);
#pragma unroll
        for (int g = 0; g < 3; ++g) {
            const int ai = (g == 2) ? NIDX : g;
#pragma unroll
            for (int nt = 0; nt < NT; ++nt) {
                short8 bf = *(const short8*)(wp + (size_t)(g * H_ + nt * 16) * H_ + k);
                acc[ai][nt] = __builtin_amdgcn_mfma_f32_16x16x32_bf16(af, bf, acc[ai][nt], 0, 0, 0);
            }
        }
    }
}

// Persistent 2-layer GRU scan, pipelined: slot s runs L0(t=s) on blocks 0..15
// (32 cols each) concurrently with L1(t=s-1) on blocks 16..47 (16 cols each).
// One grid barrier per slot. Ping-pong state buffers indexed by t&1.
// gi holds x@Wih0 + bih0 precomputed per timestep (layer 0 input part).
__global__ __launch_bounds__(256, 1)
void scan_rnn(const unsigned short* __restrict__ Whh0,
              const unsigned short* __restrict__ Wih1,
              const unsigned short* __restrict__ Whh1,
              const float* __restrict__ gi,
              const float* __restrict__ bih1,
              const float* __restrict__ bhh0,
              const float* __restrict__ bhh1,
              float* __restrict__ h0f0, float* __restrict__ h0f1,
              unsigned short* __restrict__ h0b0, unsigned short* __restrict__ h0b1,
              float* __restrict__ h1f0, float* __restrict__ h1f1,
              unsigned short* __restrict__ h1b0, unsigned short* __restrict__ h1b1,
              unsigned short* __restrict__ n0b0, unsigned short* __restrict__ n0b1,
              unsigned short* __restrict__ ys,
              const int* __restrict__ lens,
              unsigned* __restrict__ bar, unsigned bar_base, int nsteps)
{
    const int tid   = threadIdx.x;
    const int bid   = blockIdx.x;
    const int wv    = tid >> 6;
    const int lane  = tid & 63;
    const int quad  = lane >> 4;
    const int l16   = lane & 15;
    const int quad8 = quad * 8;
    const int rowA  = wv * 16 + l16;
    const bool isL0 = bid < 16;
    const int j0    = isL0 ? bid * 32 : (bid - 16) * 16;
    const f4 zz = {0.f, 0.f, 0.f, 0.f};

    for (int s = 0; s <= nsteps; ++s) {
        if (s) gsync(bar, bar_base + (unsigned)(NBLK_ * s));

        if (isL0) {
            const int t = s;
            if (t >= nsteps) continue;
            const int pi = t & 1;                 // read buf[pi], write buf[1-pi]
            const unsigned short* Ab = pi ? h0b1 : h0b0;
            const float*    hpf = pi ? h0f1 : h0f0;
            float*          hof = pi ? h0f0 : h0f1;
            unsigned short* hob = pi ? h0b0 : h0b1;
            unsigned short* nob = pi ? n0b1 : n0b0;   // n0 written to slot-parity buf

            f4 acc[4][2];
#pragma unroll
            for (int a = 0; a < 4; ++a) { acc[a][0] = zz; acc[a][1] = zz; }
            gphase<2, 3>(acc, Ab, Whh0, rowA, j0 + l16, quad8);

            const float* giT = gi + (size_t)t * (B_ * G_);
#pragma unroll
            for (int nt = 0; nt < 2; ++nt) {
                const int j = j0 + nt * 16 + l16;
                const float br = bhh0[j], bz = bhh0[j + H_], bn = bhh0[j + 2 * H_];
#pragma unroll
                for (int r = 0; r < 4; ++r) {
                    const int m = wv * 16 + quad * 4 + r;
                    const float* g = giT + (size_t)m * G_;
                    float pr  = acc[0][nt][r] + br + g[j];
                    float pz  = acc[1][nt][r] + bz + g[j + H_];
                    float inn = g[j + 2 * H_];
                    float hn  = acc[3][nt][r] + bn;
                    float rg = 1.f / (1.f + expf(-pr));
                    float zg = 1.f / (1.f + expf(-pz));
                    float ng = tanhf(inn + rg * hn);
                    float hp = hpf[m * H_ + j];
                    float hnew = (1.f - zg) * ng + zg * hp;
                    nob[m * H_ + j] = f2bf(hnew);        // unmasked n0 -> layer 1
                    float hw = hnew;
                    if (lens && t >= lens[m]) hw = hp;   // encoder length mask
                    hof[m * H_ + j] = hw;
                    hob[m * H_ + j] = f2bf(hw);
                }
            }
        } else {
            const int t = s - 1;
            if (t < 0) continue;
            const int pi = t & 1;
            const unsigned short* xb = pi ? n0b1 : n0b0;  // n0(t) written last slot
            const unsigned short* hb = pi ? h1b1 : h1b0;
            const float*    hpf = pi ? h1f1 : h1f0;
            float*          hof = pi ? h1f0 : h1f1;
            unsigned short* hob = pi ? h1b0 : h1b1;

            f4 acc[4][2];
#pragma unroll
            for (int a = 0; a < 4; ++a) { acc[a][0] = zz; acc[a][1] = zz; }
            gphase<1, 2>(acc, xb, Wih1, rowA, j0 + l16, quad8);   // input part  -> acc[2]
            gphase<1, 3>(acc, hb, Whh1, rowA, j0 + l16, quad8);   // hidden part -> acc[3]

            const int j = j0 + l16;
            const float br  = bhh1[j] + bih1[j];
            const float bz  = bhh1[j + H_] + bih1[j + H_];
            const float bin = bih1[j + 2 * H_];
            const float bhn = bhh1[j + 2 * H_];
#pragma unroll
            for (int r = 0; r < 4; ++r) {
                const int m = wv * 16 + quad * 4 + r;
                float pr  = acc[0][0][r] + br;
                float pz  = acc[1][0][r] + bz;
                float inn = acc[2][0][r] + bin;
                float hn  = acc[3][0][r] + bhn;
                float rg = 1.f / (1.f + expf(-pr));
                float zg = 1.f / (1.f + expf(-pz));
                float ng = tanhf(inn + rg * hn);
                float hp = hpf[m * H_ + j];
                float hnew = (1.f - zg) * ng + zg * hp;
                if (ys) ys[((size_t)t * B_ + m) * H_ + j] = f2bf(hnew);  // decoder output
                float hw = hnew;
                if (lens && t >= lens[m]) hw = hp;
                hof[m * H_ + j] = hw;
                hob[m * H_ + j] = f2bf(hw);
            }
        }
    }
}

// ---------------------------------------------------------------- launch
static inline void cvt(const float* s, unsigned short* d, int n, hipStream_t st) {
    int n4 = n / 4;
    cvt_bf16<<<dim3((n4 + 255) / 256), 256, 0, st>>>(s, d, n4);
}

extern "C" void kernel_launch(void* const* d_in, const int* in_sizes, int n_in,
                              void* d_out, int out_size, void* d_ws, size_t ws_size,
                              hipStream_t stream)
{
    const int* source  = (const int*)d_in[0];
    const int* target  = (const int*)d_in[1];
    const int* src_len = (const int*)d_in[2];
    const float* enc_emb  = (const float*)d_in[3];
    const float* enc_Wih0 = (const float*)d_in[4];
    const float* enc_Whh0 = (const float*)d_in[5];
    const float* enc_bih0 = (const float*)d_in[6];
    const float* enc_bhh0 = (const float*)d_in[7];
    const float* enc_Wih1 = (const float*)d_in[8];
    const float* enc_Whh1 = (const float*)d_in[9];
    const float* enc_bih1 = (const float*)d_in[10];
    const float* enc_bhh1 = (const float*)d_in[11];
    const float* dec_emb  = (const float*)d_in[12];
    const float* dec_Wih0 = (const float*)d_in[13];
    const float* dec_Whh0 = (const float*)d_in[14];
    const float* dec_bih0 = (const float*)d_in[15];
    const float* dec_bhh0 = (const float*)d_in[16];
    const float* dec_Wih1 = (const float*)d_in[17];
    const float* dec_Whh1 = (const float*)d_in[18];
    const float* dec_bih1 = (const float*)d_in[19];
    const float* dec_bhh1 = (const float*)d_in[20];
    const float* fc_W     = (const float*)d_in[21];
    const float* fc_b     = (const float*)d_in[22];
    float* out = (float*)d_out;

    const size_t BH = (size_t)B_ * H_;   // 32768

    // ---- workspace layout (bytes) ----
    char* w = (char*)d_ws;
    float* h0f0 = (float*)w;          w += BH * 4;
    float* h1f0 = (float*)w;          w += BH * 4;
    unsigned short* h0b0 = (unsigned short*)w; w += BH * 2;
    unsigned short* h1b0 = (unsigned short*)w; w += BH * 2;   // [0 .. 3*BH*4) zeroed
    unsigned* bar = (unsigned*)w;     w += 256;               // barrier counter (zeroed too)
    float* h0f1 = (float*)w;          w += BH * 4;
    float* h1f1 = (float*)w;          w += BH * 4;
    unsigned short* h0b1 = (unsigned short*)w; w += BH * 2;
    unsigned short* h1b1 = (unsigned short*)w; w += BH * 2;
    unsigned short* n0b0 = (unsigned short*)w; w += BH * 2;
    unsigned short* n0b1 = (unsigned short*)w; w += BH * 2;
    float* gi_buf = (float*)w;                w += (size_t)S_ * B_ * G_ * 4;
    unsigned short* ys = (unsigned short*)w;  w += (size_t)(T_ - 1) * B_ * H_ * 2;
    unsigned short* eWih0b = (unsigned short*)w; w += (size_t)G_ * E_ * 2;
    unsigned short* dWih0b = (unsigned short*)w; w += (size_t)G_ * E_ * 2;
    unsigned short* eWih1b = (unsigned short*)w; w += (size_t)G_ * H_ * 2;
    unsigned short* eWhh0b = (unsigned short*)w; w += (size_t)G_ * H_ * 2;
    unsigned short* eWhh1b = (unsigned short*)w; w += (size_t)G_ * H_ * 2;
    unsigned short* dWih1b = (unsigned short*)w; w += (size_t)G_ * H_ * 2;
    unsigned short* dWhh0b = (unsigned short*)w; w += (size_t)G_ * H_ * 2;
    unsigned short* dWhh1b = (unsigned short*)w; w += (size_t)G_ * H_ * 2;
    unsigned short* fcWb   = (unsigned short*)w;

    // weight conversions (fp32 -> bf16)
    cvt(enc_Wih0, eWih0b, G_ * E_, stream);
    cvt(dec_Wih0, dWih0b, G_ * E_, stream);
    cvt(enc_Wih1, eWih1b, G_ * H_, stream);
    cvt(enc_Whh0, eWhh0b, G_ * H_, stream);
    cvt(enc_Whh1, eWhh1b, G_ * H_, stream);
    cvt(dec_Wih1, dWih1b, G_ * H_, stream);
    cvt(dec_Whh0, dWhh0b, G_ * H_, stream);
    cvt(dec_Whh1, dWhh1b, G_ * H_, stream);
    cvt(fc_W,     fcWb,   VOUT_ * H_, stream);

    // zero initial states + barrier counter: contiguous 3*BH floats + 256B
    zero_f32<<<dim3((int)((3 * BH + 64 + 255) / 256)), 256, 0, stream>>>(
        (float*)d_ws, (int)(3 * BH) + 64);
    zero_out_t0<<<dim3((VOUT_ + 255) / 256, B_), 256, 0, stream>>>(out);

    // ======== encoder ========
    gemm64<<<dim3(S_ * B_ / 64, G_ / 64), 256, 0, stream>>>(
        enc_emb, nullptr, source, S_, eWih0b, enc_bih0, gi_buf, nullptr, G_, E_);

    scan_rnn<<<NBLK_, 256, 0, stream>>>(
        eWhh0b, eWih1b, eWhh1b, gi_buf, enc_bih1, enc_bhh0, enc_bhh1,
        h0f0, h0f1, h0b0, h0b1, h1f0, h1f1, h1b0, h1b1, n0b0, n0b1,
        nullptr /*ys*/, src_len, bar, 0u, S_);

    // ======== decoder ========
    gemm64<<<dim3((T_ - 1) * B_ / 64, G_ / 64), 256, 0, stream>>>(
        dec_emb, nullptr, target, T_, dWih0b, dec_bih0, gi_buf, nullptr, G_, E_);

    scan_rnn<<<NBLK_, 256, 0, stream>>>(
        dWhh0b, dWih1b, dWhh1b, gi_buf, dec_bih1, dec_bhh0, dec_bhh1,
        h0f0, h0f1, h0b0, h0b1, h1f0, h1f1, h1b0, h1b1, n0b0, n0b1,
        ys, nullptr /*lens*/, bar, (unsigned)(NBLK_ * S_), T_ - 1);

    // ======== logits = ys @ fc_W^T + fc_b -> out[b, t+1, :] ========
    gemm64<<<dim3((T_ - 1) * B_ / 64, VOUT_ / 64), 256, 0, stream>>>(
        nullptr, ys, nullptr, 0, fcWb, fc_b, nullptr, out, VOUT_, H_);
}

// Round 2
// 1814.032 us; speedup vs baseline: 3.4759x; 1.6503x over previous
//
#include <hip/hip_runtime.h>

#define B_    64
#define S_    48
#define T_    48
#define E_    256
#define H_    512
#define G_    1536   // 3*H
#define VOUT_ 32000
#define NBLK_ 48     // persistent scan: 16 L0-blocks + 32 L1-blocks

typedef __attribute__((ext_vector_type(8))) short short8;
typedef __attribute__((ext_vector_type(4))) float f4;

__device__ inline unsigned short f2bf(float f) {
    unsigned u = __float_as_uint(f);
    u += 0x7fffu + ((u >> 16) & 1u);   // RNE
    return (unsigned short)(u >> 16);
}
__device__ inline unsigned pack2(float a, float b) {
    return (unsigned)f2bf(a) | ((unsigned)f2bf(b) << 16);
}

// ---------------------------------------------------------------- utility
__global__ void zero_f32(float* p, int n) {
    int i = blockIdx.x * 256 + threadIdx.x;
    if (i < n) p[i] = 0.f;
}

__global__ void zero_out_t0(float* out) {
    int v = blockIdx.x * 256 + threadIdx.x;
    int b = blockIdx.y;
    if (v < VOUT_) out[(size_t)b * T_ * VOUT_ + v] = 0.f;
}

// fp32 -> bf16, 4 elements/thread
__global__ void cvt_bf16(const float* __restrict__ s, unsigned short* __restrict__ d, int n4) {
    int i = blockIdx.x * 256 + threadIdx.x;
    if (i < n4) {
        float4 v = ((const float4*)s)[i];
        uint2 o;
        o.x = pack2(v.x, v.y);
        o.y = pack2(v.z, v.w);
        ((uint2*)d)[i] = o;
    }
}

// ---------------------------------------------------------------- MFMA GEMM
// C(M,N) = A(M,K) @ W(N,K)^T + bias   (used for gi precompute + logits)
__global__ __launch_bounds__(256)
void gemm64(const float* __restrict__ aF,
            const unsigned short* __restrict__ aB,
            const int* __restrict__ idx, int idx_stride,
            const unsigned short* __restrict__ Wb,
            const float* __restrict__ bias,
            float* __restrict__ outF,
            float* __restrict__ outR,
            int N, int K)
{
    __shared__ __align__(16) short As[64][40];
    __shared__ __align__(16) short Ws[64][40];
    const int tid  = threadIdx.x;
    const int m0   = blockIdx.x * 64;
    const int n0   = blockIdx.y * 64;
    const int row  = tid >> 2;
    const int col8 = (tid & 3) * 8;

    const float* apF = nullptr;
    const unsigned short* apB = nullptr;
    {
        int m = m0 + row;
        if (aF) {
            size_t r;
            if (idx) { int tt = m >> 6, b = m & 63; r = (size_t)idx[b * idx_stride + tt]; }
            else     { r = (size_t)m; }
            apF = aF + r * K + col8;
        } else {
            apB = aB + (size_t)m * K + col8;
        }
    }
    const unsigned short* wp = Wb + (size_t)(n0 + row) * K + col8;

    f4 acc[4];
    const f4 zz = {0.f, 0.f, 0.f, 0.f};
    acc[0] = zz; acc[1] = zz; acc[2] = zz; acc[3] = zz;

    const int wv   = tid >> 6;
    const int lane = tid & 63;
    const int quad = lane >> 4;
    const int l16  = lane & 15;

    for (int k0 = 0; k0 < K; k0 += 32) {
        uint4 av;
        if (apF) {
            float4 v0 = *(const float4*)(apF + k0);
            float4 v1 = *(const float4*)(apF + k0 + 4);
            av.x = pack2(v0.x, v0.y);
            av.y = pack2(v0.z, v0.w);
            av.z = pack2(v1.x, v1.y);
            av.w = pack2(v1.z, v1.w);
        } else {
            av = *(const uint4*)(apB + k0);
        }
        uint4 wvv = *(const uint4*)(wp + k0);
        *(uint4*)&As[row][col8] = av;
        *(uint4*)&Ws[row][col8] = wvv;
        __syncthreads();
        short8 afrag = *(const short8*)&As[wv * 16 + l16][quad * 8];
#pragma unroll
        for (int nt = 0; nt < 4; ++nt) {
            short8 bfrag = *(const short8*)&Ws[nt * 16 + l16][quad * 8];
            acc[nt] = __builtin_amdgcn_mfma_f32_16x16x32_bf16(afrag, bfrag, acc[nt], 0, 0, 0);
        }
        __syncthreads();
    }

#pragma unroll
    for (int nt = 0; nt < 4; ++nt) {
#pragma unroll
        for (int r = 0; r < 4; ++r) {
            int mm = m0 + wv * 16 + quad * 4 + r;
            int nn = n0 + nt * 16 + l16;
            float v = acc[nt][r];
            if (bias) v += bias[nn];
            if (outF) {
                outF[(size_t)mm * N + nn] = v;
            } else {
                int tt = mm >> 6, b = mm & 63;             // mm = t*64 + b
                outR[((size_t)b * T_ + tt + 1) * VOUT_ + nn] = v;
            }
        }
    }
}

// ---------------------------------------------------------------- persistent RNN scan
// Grid-wide barrier: monotonic counter, device(agent)-scope atomics.
// All NBLK_ (=48) blocks are trivially co-resident (48 << 256 CUs).
__device__ __forceinline__ void gsync(unsigned* bar, unsigned target) {
    __syncthreads();
    if (threadIdx.x == 0) {
        __threadfence();
        __hip_atomic_fetch_add(bar, 1u, __ATOMIC_RELAXED, __HIP_MEMORY_SCOPE_AGENT);
        while (__hip_atomic_load(bar, __ATOMIC_RELAXED, __HIP_MEMORY_SCOPE_AGENT) < target) {
            __builtin_amdgcn_s_sleep(1);
        }
        __threadfence();
    }
    __syncthreads();
}

// Persistent 2-layer GRU scan, pipelined: slot s runs L0(t=s) on blocks 0..15
// (32 cols x 3 gates each) concurrently with L1(t=s-1) on blocks 16..47
// (16 cols x 3 gates x 2 phases each). One grid barrier per slot.
//
// Weights: staged ONCE into LDS in fragment-major layout Wl[frag][lane]
// (1 KiB contiguous per fragment -> conflict-free ds_read_b128, all per-slot
// B-operand reads are LDS hits instead of L2/L3 misses).
// h-state (f32, exact) lives in REGISTERS across timesteps (each block's
// epilogue reads only the h it wrote). Only bf16 A-operands cross blocks.
// gi (precomputed, read-only) is prefetched BEFORE the grid barrier so HBM
// latency hides under the spin. Encoder<->decoder handoff via h0F/h1F (f32),
// written on the final step only.
__global__ __launch_bounds__(256, 1)
void scan_rnn(const unsigned short* __restrict__ Whh0,
              const unsigned short* __restrict__ Wih1,
              const unsigned short* __restrict__ Whh1,
              const float* __restrict__ gi,
              const float* __restrict__ bih1,
              const float* __restrict__ bhh0,
              const float* __restrict__ bhh1,
              float* __restrict__ h0F, float* __restrict__ h1F,
              unsigned short* __restrict__ h0b0, unsigned short* __restrict__ h0b1,
              unsigned short* __restrict__ h1b0, unsigned short* __restrict__ h1b1,
              unsigned short* __restrict__ n0b0, unsigned short* __restrict__ n0b1,
              unsigned short* __restrict__ ys,
              const int* __restrict__ lens,
              unsigned* __restrict__ bar, unsigned bar_base, int nsteps)
{
    __shared__ __align__(16) short8 Wl[96][64];   // 96 KiB, fragment-major

    const int tid   = threadIdx.x;
    const int bid   = blockIdx.x;
    const int wv    = tid >> 6;
    const int lane  = tid & 63;
    const int quad  = lane >> 4;
    const int l16   = lane & 15;
    const int quad8 = quad * 8;
    const int rowA  = wv * 16 + l16;
    const int mrow  = wv * 16 + quad * 4;
    const bool isL0 = bid < 16;
    const int j0    = isL0 ? bid * 32 : (bid - 16) * 16;
    const f4 zz = {0.f, 0.f, 0.f, 0.f};

    // ---- one-time: stage this block's weight slice into LDS ----
    // L0 frag f = kiter*6 + g*2 + nt ; L1 frag f = p*48 + kiter*3 + g
#pragma unroll 4
    for (int i = 0; i < 24; ++i) {
        const int f = wv * 24 + i;
        const unsigned short* src;
        if (isL0) {
            int kiter = f / 6, rem = f % 6, g = rem >> 1, nt = rem & 1;
            src = Whh0 + (size_t)(g * H_ + j0 + nt * 16 + l16) * H_ + kiter * 32 + quad8;
        } else {
            int p = f / 48, rem = f % 48, kiter = rem / 3, g = rem % 3;
            const unsigned short* W = p ? Whh1 : Wih1;
            src = W + (size_t)(g * H_ + j0 + l16) * H_ + kiter * 32 + quad8;
        }
        Wl[f][lane] = *(const short8*)src;
    }
    __syncthreads();

    // ---- one-time: hoist biases, lens, initial h (f32) into registers ----
    int lenm[4];
#pragma unroll
    for (int r = 0; r < 4; ++r) lenm[r] = lens ? lens[mrow + r] : 0x7fffffff;

    float b0r[2], b0z[2], b0n[2], h0r[2][4];
    float b1r = 0.f, b1z = 0.f, b1in = 0.f, b1hn = 0.f, h1r[4];
    if (isL0) {
#pragma unroll
        for (int nt = 0; nt < 2; ++nt) {
            const int j = j0 + nt * 16 + l16;
            b0r[nt] = bhh0[j]; b0z[nt] = bhh0[j + H_]; b0n[nt] = bhh0[j + 2 * H_];
#pragma unroll
            for (int r = 0; r < 4; ++r) h0r[nt][r] = h0F[(mrow + r) * H_ + j];
        }
    } else {
        const int j = j0 + l16;
        b1r  = bhh1[j] + bih1[j];
        b1z  = bhh1[j + H_] + bih1[j + H_];
        b1in = bih1[j + 2 * H_];
        b1hn = bhh1[j + 2 * H_];
#pragma unroll
        for (int r = 0; r < 4; ++r) h1r[r] = h1F[(mrow + r) * H_ + j];
    }

    for (int s = 0; s <= nsteps; ++s) {
        // gi prefetch: barrier-independent (precomputed), HBM latency hides
        // under the spin.
        float gir[2][4], giz[2][4], gin[2][4];
        if (isL0 && s < nsteps) {
            const float* giT = gi + (size_t)s * (B_ * G_);
#pragma unroll
            for (int nt = 0; nt < 2; ++nt) {
                const int j = j0 + nt * 16 + l16;
#pragma unroll
                for (int r = 0; r < 4; ++r) {
                    const float* g = giT + (size_t)(mrow + r) * G_;
                    gir[nt][r] = g[j];
                    giz[nt][r] = g[j + H_];
                    gin[nt][r] = g[j + 2 * H_];
                }
            }
        }
        if (s) gsync(bar, bar_base + (unsigned)(NBLK_ * s));

        if (isL0) {
            const int t = s;
            if (t >= nsteps) continue;
            const int pi = t & 1;
            const unsigned short* Ab = pi ? h0b1 : h0b0;
            unsigned short* hob = pi ? h0b0 : h0b1;
            unsigned short* nob = pi ? n0b1 : n0b0;

            short8 av[16];
#pragma unroll
            for (int k = 0; k < 16; ++k)
                av[k] = *(const short8*)(Ab + (size_t)rowA * H_ + k * 32 + quad8);

            f4 acc[4][2];
#pragma unroll
            for (int a = 0; a < 4; ++a) { acc[a][0] = zz; acc[a][1] = zz; }
#pragma unroll
            for (int k = 0; k < 16; ++k) {
#pragma unroll
                for (int g = 0; g < 3; ++g) {
                    const int ai = (g == 2) ? 3 : g;
#pragma unroll
                    for (int nt = 0; nt < 2; ++nt) {
                        acc[ai][nt] = __builtin_amdgcn_mfma_f32_16x16x32_bf16(
                            av[k], Wl[k * 6 + g * 2 + nt][lane], acc[ai][nt], 0, 0, 0);
                    }
                }
            }

#pragma unroll
            for (int nt = 0; nt < 2; ++nt) {
                const int j = j0 + nt * 16 + l16;
#pragma unroll
                for (int r = 0; r < 4; ++r) {
                    const int m = mrow + r;
                    float pr = acc[0][nt][r] + b0r[nt] + gir[nt][r];
                    float pz = acc[1][nt][r] + b0z[nt] + giz[nt][r];
                    float hn = acc[3][nt][r] + b0n[nt];
                    float rg = 1.f / (1.f + expf(-pr));
                    float zg = 1.f / (1.f + expf(-pz));
                    float ng = tanhf(gin[nt][r] + rg * hn);
                    float hp = h0r[nt][r];
                    float hnew = (1.f - zg) * ng + zg * hp;
                    nob[m * H_ + j] = f2bf(hnew);          // unmasked n0 -> layer 1
                    float hw = (t >= lenm[r]) ? hp : hnew; // encoder length mask
                    h0r[nt][r] = hw;
                    hob[m * H_ + j] = f2bf(hw);
                    if (t == nsteps - 1) h0F[m * H_ + j] = hw;
                }
            }
        } else {
            const int t = s - 1;
            if (t < 0) continue;
            const int pi = t & 1;
            const unsigned short* xb = pi ? n0b1 : n0b0;
            const unsigned short* hb = pi ? h1b1 : h1b0;
            unsigned short* hob = pi ? h1b0 : h1b1;

            short8 av0[16], av1[16];
#pragma unroll
            for (int k = 0; k < 16; ++k) {
                av0[k] = *(const short8*)(xb + (size_t)rowA * H_ + k * 32 + quad8);
                av1[k] = *(const short8*)(hb + (size_t)rowA * H_ + k * 32 + quad8);
            }

            f4 acc[4];
#pragma unroll
            for (int a = 0; a < 4; ++a) acc[a] = zz;
#pragma unroll
            for (int k = 0; k < 16; ++k) {
#pragma unroll
                for (int g = 0; g < 3; ++g) {
                    const int ai = (g == 2) ? 2 : g;   // input n-part
                    acc[ai] = __builtin_amdgcn_mfma_f32_16x16x32_bf16(
                        av0[k], Wl[k * 3 + g][lane], acc[ai], 0, 0, 0);
                }
            }
#pragma unroll
            for (int k = 0; k < 16; ++k) {
#pragma unroll
                for (int g = 0; g < 3; ++g) {
                    const int ai = (g == 2) ? 3 : g;   // hidden n-part
                    acc[ai] = __builtin_amdgcn_mfma_f32_16x16x32_bf16(
                        av1[k], Wl[48 + k * 3 + g][lane], acc[ai], 0, 0, 0);
                }
            }

            const int j = j0 + l16;
#pragma unroll
            for (int r = 0; r < 4; ++r) {
                const int m = mrow + r;
                float pr  = acc[0][r] + b1r;
                float pz  = acc[1][r] + b1z;
                float inn = acc[2][r] + b1in;
                float hn  = acc[3][r] + b1hn;
                float rg = 1.f / (1.f + expf(-pr));
                float zg = 1.f / (1.f + expf(-pz));
                float ng = tanhf(inn + rg * hn);
                float hp = h1r[r];
                float hnew = (1.f - zg) * ng + zg * hp;
                if (ys) ys[((size_t)t * B_ + m) * H_ + j] = f2bf(hnew);
                float hw = (t >= lenm[r]) ? hp : hnew;
                h1r[r] = hw;
                hob[m * H_ + j] = f2bf(hw);
                if (t == nsteps - 1) h1F[m * H_ + j] = hw;
            }
        }
    }
}

// ---------------------------------------------------------------- launch
static inline void cvt(const float* s, unsigned short* d, int n, hipStream_t st) {
    int n4 = n / 4;
    cvt_bf16<<<dim3((n4 + 255) / 256), 256, 0, st>>>(s, d, n4);
}

extern "C" void kernel_launch(void* const* d_in, const int* in_sizes, int n_in,
                              void* d_out, int out_size, void* d_ws, size_t ws_size,
                              hipStream_t stream)
{
    const int* source  = (const int*)d_in[0];
    const int* target  = (const int*)d_in[1];
    const int* src_len = (const int*)d_in[2];
    const float* enc_emb  = (const float*)d_in[3];
    const float* enc_Wih0 = (const float*)d_in[4];
    const float* enc_Whh0 = (const float*)d_in[5];
    const float* enc_bih0 = (const float*)d_in[6];
    const float* enc_bhh0 = (const float*)d_in[7];
    const float* enc_Wih1 = (const float*)d_in[8];
    const float* enc_Whh1 = (const float*)d_in[9];
    const float* enc_bih1 = (const float*)d_in[10];
    const float* enc_bhh1 = (const float*)d_in[11];
    const float* dec_emb  = (const float*)d_in[12];
    const float* dec_Wih0 = (const float*)d_in[13];
    const float* dec_Whh0 = (const float*)d_in[14];
    const float* dec_bih0 = (const float*)d_in[15];
    const float* dec_bhh0 = (const float*)d_in[16];
    const float* dec_Wih1 = (const float*)d_in[17];
    const float* dec_Whh1 = (const float*)d_in[18];
    const float* dec_bih1 = (const float*)d_in[19];
    const float* dec_bhh1 = (const float*)d_in[20];
    const float* fc_W     = (const float*)d_in[21];
    const float* fc_b     = (const float*)d_in[22];
    float* out = (float*)d_out;

    const size_t BH = (size_t)B_ * H_;   // 32768

    // ---- workspace layout (bytes) ----
    char* w = (char*)d_ws;
    float* h0F = (float*)w;           w += BH * 4;
    float* h1F = (float*)w;           w += BH * 4;
    unsigned short* h0b0 = (unsigned short*)w; w += BH * 2;
    unsigned short* h1b0 = (unsigned short*)w; w += BH * 2;
    unsigned* bar = (unsigned*)w;     w += 256;          // [0 .. 3*BH*4+256) zeroed
    unsigned short* h0b1 = (unsigned short*)w; w += BH * 2;
    unsigned short* h1b1 = (unsigned short*)w; w += BH * 2;
    unsigned short* n0b0 = (unsigned short*)w; w += BH * 2;
    unsigned short* n0b1 = (unsigned short*)w; w += BH * 2;
    float* gi_buf = (float*)w;                w += (size_t)S_ * B_ * G_ * 4;
    unsigned short* ys = (unsigned short*)w;  w += (size_t)(T_ - 1) * B_ * H_ * 2;
    unsigned short* eWih0b = (unsigned short*)w; w += (size_t)G_ * E_ * 2;
    unsigned short* dWih0b = (unsigned short*)w; w += (size_t)G_ * E_ * 2;
    unsigned short* eWih1b = (unsigned short*)w; w += (size_t)G_ * H_ * 2;
    unsigned short* eWhh0b = (unsigned short*)w; w += (size_t)G_ * H_ * 2;
    unsigned short* eWhh1b = (unsigned short*)w; w += (size_t)G_ * H_ * 2;
    unsigned short* dWih1b = (unsigned short*)w; w += (size_t)G_ * H_ * 2;
    unsigned short* dWhh0b = (unsigned short*)w; w += (size_t)G_ * H_ * 2;
    unsigned short* dWhh1b = (unsigned short*)w; w += (size_t)G_ * H_ * 2;
    unsigned short* fcWb   = (unsigned short*)w;

    // weight conversions (fp32 -> bf16)
    cvt(enc_Wih0, eWih0b, G_ * E_, stream);
    cvt(dec_Wih0, dWih0b, G_ * E_, stream);
    cvt(enc_Wih1, eWih1b, G_ * H_, stream);
    cvt(enc_Whh0, eWhh0b, G_ * H_, stream);
    cvt(enc_Whh1, eWhh1b, G_ * H_, stream);
    cvt(dec_Wih1, dWih1b, G_ * H_, stream);
    cvt(dec_Whh0, dWhh0b, G_ * H_, stream);
    cvt(dec_Whh1, dWhh1b, G_ * H_, stream);
    cvt(fc_W,     fcWb,   VOUT_ * H_, stream);

    // zero initial states (h0F,h1F f32 + h0b0,h1b0 bf16) + barrier counter:
    // contiguous 3*BH floats + 256 B
    zero_f32<<<dim3((int)((3 * BH + 64 + 255) / 256)), 256, 0, stream>>>(
        (float*)d_ws, (int)(3 * BH) + 64);
    zero_out_t0<<<dim3((VOUT_ + 255) / 256, B_), 256, 0, stream>>>(out);

    // ======== encoder ========
    gemm64<<<dim3(S_ * B_ / 64, G_ / 64), 256, 0, stream>>>(
        enc_emb, nullptr, source, S_, eWih0b, enc_bih0, gi_buf, nullptr, G_, E_);

    scan_rnn<<<NBLK_, 256, 0, stream>>>(
        eWhh0b, eWih1b, eWhh1b, gi_buf, enc_bih1, enc_bhh0, enc_bhh1,
        h0F, h1F, h0b0, h0b1, h1b0, h1b1, n0b0, n0b1,
        nullptr /*ys*/, src_len, bar, 0u, S_);

    // ======== decoder ========
    gemm64<<<dim3((T_ - 1) * B_ / 64, G_ / 64), 256, 0, stream>>>(
        dec_emb, nullptr, target, T_, dWih0b, dec_bih0, gi_buf, nullptr, G_, E_);

    scan_rnn<<<NBLK_, 256, 0, stream>>>(
        dWhh0b, dWih1b, dWhh1b, gi_buf, dec_bih1, dec_bhh0, dec_bhh1,
        h0F, h1F, h0b0, h0b1, h1b0, h1b1, n0b0, n0b1,
        ys, nullptr /*lens*/, bar, (unsigned)(NBLK_ * S_), T_ - 1);

    // ======== logits = ys @ fc_W^T + fc_b -> out[b, t+1, :] ========
    gemm64<<<dim3((T_ - 1) * B_ / 64, VOUT_ / 64), 256, 0, stream>>>(
        nullptr, ys, nullptr, 0, fcWb, fc_b, nullptr, out, VOUT_, H_);
}